// Round 1
// baseline (556.289 us; speedup 1.0000x reference)
//
#include <hip/hip_runtime.h>
#include <math.h>

#define E 1024
#define H 16
#define HD 64
#define B 32
#define S 2048
#define PSPLIT 16
#define PCHUNK (S / PSPLIT)  // 128

// ---------------------------------------------------------------- q = Wq @ seed + bq
// wave per output element e (1024 waves). 256 blocks x 256 threads.
__global__ __launch_bounds__(256) void qproj_kernel(const float* __restrict__ W,
                                                    const float* __restrict__ bqkv,
                                                    const float* __restrict__ seed,
                                                    float* __restrict__ q) {
    int gw = (blockIdx.x * 256 + threadIdx.x) >> 6;  // e index
    int lane = threadIdx.x & 63;
    if (gw >= E) return;
    const float4* row = (const float4*)(W + (size_t)gw * E);
    const float4* sd = (const float4*)seed;
    float acc = 0.f;
#pragma unroll
    for (int k = 0; k < 4; ++k) {
        float4 w4 = row[k * 64 + lane];
        float4 s4 = sd[k * 64 + lane];
        acc = fmaf(w4.x, s4.x, acc); acc = fmaf(w4.y, s4.y, acc);
        acc = fmaf(w4.z, s4.z, acc); acc = fmaf(w4.w, s4.w, acc);
    }
#pragma unroll
    for (int off = 32; off > 0; off >>= 1) acc += __shfl_down(acc, off, 64);
    if (lane == 0) q[gw] = acc + bqkv[gw];
}

// ---------------------------------------------------------------- u[h][e] = scale * sum_d q[h*64+d] * Wk[h*64+d][e]
__global__ __launch_bounds__(256) void uproj_kernel(const float* __restrict__ W,
                                                    const float* __restrict__ q,
                                                    float* __restrict__ u) {
    int h = blockIdx.y;
    int e = blockIdx.x * 256 + threadIdx.x;
    __shared__ float qs[HD];
    if (threadIdx.x < HD) qs[threadIdx.x] = q[h * HD + threadIdx.x];
    __syncthreads();
    const float* Wk = W + ((size_t)(E + h * HD)) * E + e;
    float acc = 0.f;
#pragma unroll 8
    for (int d = 0; d < HD; ++d) acc = fmaf(qs[d], Wk[(size_t)d * E], acc);
    u[h * E + e] = acc * 0.125f;  // 1/sqrt(64)
}

// ---------------------------------------------------------------- scores[b][h][s] = u[h] . x[b][s]
// wave per token, 16 tokens per wave, 4 waves/block. u staged in 64KB LDS.
__global__ __launch_bounds__(256) void scores_kernel(const float* __restrict__ x,
                                                     const float* __restrict__ u,
                                                     float* __restrict__ scores) {
    __shared__ float us[H * E];  // 64 KB
    for (int i = threadIdx.x; i < H * E / 4; i += 256)
        ((float4*)us)[i] = ((const float4*)u)[i];
    __syncthreads();
    int wid = threadIdx.x >> 6, lane = threadIdx.x & 63;
    int wave = blockIdx.x * 4 + wid;
    const float4* us4 = (const float4*)us;
    for (int tt = 0; tt < 16; ++tt) {
        int tok = wave * 16 + tt;
        int b = tok >> 11, s = tok & (S - 1);
        const float4* xr = (const float4*)(x + (size_t)tok * E);
        float4 x4[4];
#pragma unroll
        for (int k = 0; k < 4; ++k) x4[k] = xr[k * 64 + lane];
        float acc[H];
#pragma unroll
        for (int h = 0; h < H; ++h) {
            float a = 0.f;
#pragma unroll
            for (int k = 0; k < 4; ++k) {
                float4 uv = us4[h * 256 + k * 64 + lane];
                a = fmaf(x4[k].x, uv.x, a); a = fmaf(x4[k].y, uv.y, a);
                a = fmaf(x4[k].z, uv.z, a); a = fmaf(x4[k].w, uv.w, a);
            }
            acc[h] = a;
        }
#pragma unroll
        for (int off = 32; off > 0; off >>= 1) {
#pragma unroll
            for (int h = 0; h < H; ++h) acc[h] += __shfl_down(acc[h], off, 64);
        }
        if (lane == 0) {
#pragma unroll
            for (int h = 0; h < H; ++h) scores[((size_t)(b * H + h)) * S + s] = acc[h];
        }
    }
}

// ---------------------------------------------------------------- masked softmax over S per (b,h)
__global__ __launch_bounds__(256) void softmax_kernel(float* __restrict__ scores,
                                                      const int* __restrict__ mask) {
    int bh = blockIdx.x;
    int b = bh >> 4;
    float* row = scores + (size_t)bh * S;
    const int* mrow = mask + (size_t)b * S;
    int t = threadIdx.x, lane = t & 63, wid = t >> 6;
    float vals[8];
    float mx = -1e30f;
#pragma unroll
    for (int i = 0; i < 8; ++i) {
        int s = i * 256 + t;
        float v = row[s];
        if (mrow[s] == 0) v = -1e30f;
        vals[i] = v;
        mx = fmaxf(mx, v);
    }
    __shared__ float redm[4], reds[4];
#pragma unroll
    for (int off = 32; off > 0; off >>= 1) mx = fmaxf(mx, __shfl_down(mx, off, 64));
    if (lane == 0) redm[wid] = mx;
    __syncthreads();
    mx = fmaxf(fmaxf(redm[0], redm[1]), fmaxf(redm[2], redm[3]));
    float sum = 0.f;
#pragma unroll
    for (int i = 0; i < 8; ++i) {
        float p = __expf(vals[i] - mx);
        vals[i] = p;
        sum += p;
    }
#pragma unroll
    for (int off = 32; off > 0; off >>= 1) sum += __shfl_down(sum, off, 64);
    if (lane == 0) reds[wid] = sum;
    __syncthreads();
    sum = reds[0] + reds[1] + reds[2] + reds[3];
    float inv = 1.f / sum;
#pragma unroll
    for (int i = 0; i < 8; ++i) row[i * 256 + t] = vals[i] * inv;
}

// ---------------------------------------------------------------- xbar[b][h][:] += sum_s attn * x  (atomic partial)
__global__ __launch_bounds__(256) void pool_kernel(const float* __restrict__ x,
                                                   const float* __restrict__ attn,
                                                   float* __restrict__ xbar) {
    int sp = blockIdx.x, b = blockIdx.y;
    int t = threadIdx.x;
    __shared__ float at[H][PCHUNK];  // 8 KB
    for (int i = t; i < H * PCHUNK; i += 256) {
        int h = i / PCHUNK, s = i % PCHUNK;
        at[h][s] = attn[((size_t)(b * H + h)) * S + sp * PCHUNK + s];
    }
    __syncthreads();
    const float4* xr = (const float4*)(x + ((size_t)(b * S) + sp * PCHUNK) * E);
    float4 acc[H];
#pragma unroll
    for (int h = 0; h < H; ++h) acc[h] = make_float4(0.f, 0.f, 0.f, 0.f);
    for (int s = 0; s < PCHUNK; ++s) {
        float4 xv = xr[(size_t)s * (E / 4) + t];
#pragma unroll
        for (int h = 0; h < H; ++h) {
            float a = at[h][s];
            acc[h].x = fmaf(a, xv.x, acc[h].x);
            acc[h].y = fmaf(a, xv.y, acc[h].y);
            acc[h].z = fmaf(a, xv.z, acc[h].z);
            acc[h].w = fmaf(a, xv.w, acc[h].w);
        }
    }
    float* xb = xbar + (size_t)b * H * E + t * 4;
#pragma unroll
    for (int h = 0; h < H; ++h) {
        atomicAdd(&xb[h * E + 0], acc[h].x);
        atomicAdd(&xb[h * E + 1], acc[h].y);
        atomicAdd(&xb[h * E + 2], acc[h].z);
        atomicAdd(&xb[h * E + 3], acc[h].w);
    }
}

// ---------------------------------------------------------------- ctx[b][c] = bv[c] + Wv[c] . xbar[b][h(c)]
__global__ __launch_bounds__(256) void ctx_kernel(const float* __restrict__ W,
                                                  const float* __restrict__ bqkv,
                                                  const float* __restrict__ xbar,
                                                  float* __restrict__ ctx) {
    int cb = blockIdx.x, b = blockIdx.y, t = threadIdx.x;
    int c = cb * 256 + t;
    int h0 = cb * 4;
    __shared__ float xls[4 * E];  // 16 KB
    const float4* xbp = (const float4*)(xbar + ((size_t)b * H + h0) * E);
    for (int i = t; i < 4 * E / 4; i += 256) ((float4*)xls)[i] = xbp[i];
    __syncthreads();
    int h = c >> 6;
    const float4* wr = (const float4*)(W + ((size_t)(2 * E + c)) * E);
    const float4* xl = (const float4*)(xls + (h - h0) * E);
    float acc = bqkv[2 * E + c];
#pragma unroll 4
    for (int e4 = 0; e4 < E / 4; ++e4) {
        float4 w = wr[e4], xv = xl[e4];
        acc = fmaf(w.x, xv.x, acc); acc = fmaf(w.y, xv.y, acc);
        acc = fmaf(w.z, xv.z, acc); acc = fmaf(w.w, xv.w, acc);
    }
    ctx[(size_t)b * E + c] = acc;
}

// ---------------------------------------------------------------- out[b][o] = ob[o] + Wo[o] . ctx[b]
__global__ __launch_bounds__(256) void outproj_kernel(const float* __restrict__ Wo,
                                                      const float* __restrict__ ob,
                                                      const float* __restrict__ ctx,
                                                      float* __restrict__ outpre) {
    int obk = blockIdx.x, b = blockIdx.y, t = threadIdx.x;
    int o = obk * 256 + t;
    __shared__ float cl[E];  // 4 KB
    const float4* cp = (const float4*)(ctx + (size_t)b * E);
    for (int i = t; i < E / 4; i += 256) ((float4*)cl)[i] = cp[i];
    __syncthreads();
    const float4* wr = (const float4*)(Wo + (size_t)o * E);
    const float4* cl4 = (const float4*)cl;
    float acc = ob[o];
#pragma unroll 4
    for (int e4 = 0; e4 < E / 4; ++e4) {
        float4 w = wr[e4], cv = cl4[e4];
        acc = fmaf(w.x, cv.x, acc); acc = fmaf(w.y, cv.y, acc);
        acc = fmaf(w.z, cv.z, acc); acc = fmaf(w.w, cv.w, acc);
    }
    outpre[(size_t)b * E + o] = acc;
}

// ---------------------------------------------------------------- LayerNorm over E per b
__global__ __launch_bounds__(256) void ln_kernel(const float* __restrict__ outpre,
                                                 const float* __restrict__ g,
                                                 const float* __restrict__ bb,
                                                 float* __restrict__ out) {
    int b = blockIdx.x, t = threadIdx.x, lane = t & 63, wid = t >> 6;
    const float4* row = (const float4*)(outpre + (size_t)b * E);
    float4 v = row[t];
    float s = v.x + v.y + v.z + v.w;
    float sq = v.x * v.x + v.y * v.y + v.z * v.z + v.w * v.w;
    __shared__ float rs[4], rq[4];
#pragma unroll
    for (int off = 32; off > 0; off >>= 1) {
        s += __shfl_down(s, off, 64);
        sq += __shfl_down(sq, off, 64);
    }
    if (lane == 0) { rs[wid] = s; rq[wid] = sq; }
    __syncthreads();
    s = rs[0] + rs[1] + rs[2] + rs[3];
    sq = rq[0] + rq[1] + rq[2] + rq[3];
    float mean = s * (1.f / E);
    float var = sq * (1.f / E) - mean * mean;
    float inv = rsqrtf(var + 1e-5f);
    float4 gv = ((const float4*)g)[t];
    float4 bv = ((const float4*)bb)[t];
    float4 o;
    o.x = (v.x - mean) * inv * gv.x + bv.x;
    o.y = (v.y - mean) * inv * gv.y + bv.y;
    o.z = (v.z - mean) * inv * gv.z + bv.z;
    o.w = (v.w - mean) * inv * gv.w + bv.w;
    ((float4*)(out + (size_t)b * E))[t] = o;
}

extern "C" void kernel_launch(void* const* d_in, const int* in_sizes, int n_in,
                              void* d_out, int out_size, void* d_ws, size_t ws_size,
                              hipStream_t stream) {
    const float* x    = (const float*)d_in[0];
    const int*   mask = (const int*)d_in[1];
    const float* seed = (const float*)d_in[2];
    const float* W    = (const float*)d_in[3];  // (3E, E)
    const float* bqkv = (const float*)d_in[4];  // (3E,)
    const float* Wo   = (const float*)d_in[5];  // (E, E)
    const float* ob   = (const float*)d_in[6];  // (E,)
    const float* g    = (const float*)d_in[7];
    const float* lb   = (const float*)d_in[8];
    float* out = (float*)d_out;

    float* ws = (float*)d_ws;
    float* q      = ws;                      // 1024
    float* u      = q + E;                   // 16384
    float* scores = u + H * E;               // B*H*S = 1,048,576
    float* xbar   = scores + (size_t)B * H * S;  // B*H*E = 524,288
    float* ctx    = xbar + (size_t)B * H * E;    // B*E
    float* outpre = ctx + (size_t)B * E;         // B*E

    hipMemsetAsync(xbar, 0, (size_t)B * H * E * sizeof(float), stream);

    qproj_kernel<<<256, 256, 0, stream>>>(W, bqkv, seed, q);
    uproj_kernel<<<dim3(E / 256, H), 256, 0, stream>>>(W, q, u);
    scores_kernel<<<(B * S) / 64, 256, 0, stream>>>(x, u, scores);
    softmax_kernel<<<B * H, 256, 0, stream>>>(scores, mask);
    pool_kernel<<<dim3(PSPLIT, B), 256, 0, stream>>>(x, scores, xbar);
    ctx_kernel<<<dim3(E / 256, B), 256, 0, stream>>>(W, bqkv, xbar, ctx);
    outproj_kernel<<<dim3(E / 256, B), 256, 0, stream>>>(Wo, ob, ctx, outpre);
    ln_kernel<<<B, 256, 0, stream>>>(outpre, g, lb, out);
}

// Round 2
// 498.396 us; speedup vs baseline: 1.1162x; 1.1162x over previous
//
#include <hip/hip_runtime.h>
#include <math.h>

#define E 1024
#define H 16
#define HD 64
#define B 32
#define S 2048
#define PSPLIT 16
#define PCHUNK (S / PSPLIT)  // 128

// ---------------------------------------------------------------- q = Wq @ seed + bq
__global__ __launch_bounds__(256) void qproj_kernel(const float* __restrict__ W,
                                                    const float* __restrict__ bqkv,
                                                    const float* __restrict__ seed,
                                                    float* __restrict__ q) {
    int gw = (blockIdx.x * 256 + threadIdx.x) >> 6;  // e index
    int lane = threadIdx.x & 63;
    if (gw >= E) return;
    const float4* row = (const float4*)(W + (size_t)gw * E);
    const float4* sd = (const float4*)seed;
    float acc = 0.f;
#pragma unroll
    for (int k = 0; k < 4; ++k) {
        float4 w4 = row[k * 64 + lane];
        float4 s4 = sd[k * 64 + lane];
        acc = fmaf(w4.x, s4.x, acc); acc = fmaf(w4.y, s4.y, acc);
        acc = fmaf(w4.z, s4.z, acc); acc = fmaf(w4.w, s4.w, acc);
    }
#pragma unroll
    for (int off = 32; off > 0; off >>= 1) acc += __shfl_down(acc, off, 64);
    if (lane == 0) q[gw] = acc + bqkv[gw];
}

// ---------------------------------------------------------------- u[h][e] = scale * sum_d q[h*64+d] * Wk[h*64+d][e]
__global__ __launch_bounds__(256) void uproj_kernel(const float* __restrict__ W,
                                                    const float* __restrict__ q,
                                                    float* __restrict__ u) {
    int h = blockIdx.y;
    int e = blockIdx.x * 256 + threadIdx.x;
    __shared__ float qs[HD];
    if (threadIdx.x < HD) qs[threadIdx.x] = q[h * HD + threadIdx.x];
    __syncthreads();
    const float* Wk = W + ((size_t)(E + h * HD)) * E + e;
    float acc = 0.f;
#pragma unroll 8
    for (int d = 0; d < HD; ++d) acc = fmaf(qs[d], Wk[(size_t)d * E], acc);
    u[h * E + e] = acc * 0.125f;  // 1/sqrt(64)
}

// ---------------------------------------------------------------- scores[b][h][s] = u[h] . x[b][s]
// v2: lane = (e-slice m, head-group g). Each wave: 4-token group, acc[4 tok][4 head].
// u in LDS as [e4][h] float4 with XOR swizzle h' = h ^ (e4&7): exactly 64 KB,
// b128 reads hit every bank exactly 8x (structural minimum, conflict-free).
// Reduction: 4-step halving butterfly over the 16 m-lanes only.
__global__ __launch_bounds__(512) void scores_kernel(const float* __restrict__ x,
                                                     const float* __restrict__ u,
                                                     float* __restrict__ scores) {
    __shared__ float4 uT[256 * 16];  // [e4][h^] -> 64 KB
    for (int idx = threadIdx.x; idx < 256 * 16; idx += 512) {
        int h = idx >> 8, e4 = idx & 255;
        uT[e4 * 16 + (h ^ (e4 & 7))] = ((const float4*)(u + (size_t)h * E))[e4];
    }
    __syncthreads();

    int lane = threadIdx.x & 63;
    int wid = threadIdx.x >> 6;           // 0..7
    int gwave = blockIdx.x * 8 + wid;     // 0..4095
    int m = lane & 15;                    // e-slice
    int g = lane >> 4;                    // head-group (heads 4g..4g+3)

    // loop-invariant swizzled LDS float4-indices for j=0..3
    int uoff[4];
#pragma unroll
    for (int j = 0; j < 4; ++j) uoff[j] = m * 16 + ((4 * g + j) ^ (m & 7));

    for (int grp = 0; grp < 4; ++grp) {
        int tb = gwave * 16 + grp * 4;    // token base (4 tokens)
        const float* xb = x + (size_t)tb * E + m * 4;
        float acc[4][4] = {{0.f}};
#pragma unroll
        for (int k = 0; k < 16; ++k) {
            float4 xv[4];
#pragma unroll
            for (int t = 0; t < 4; ++t)
                xv[t] = *(const float4*)(xb + (size_t)t * E + k * 64);
#pragma unroll
            for (int j = 0; j < 4; ++j) {
                float4 uv = uT[k * 256 + uoff[j]];
#pragma unroll
                for (int t = 0; t < 4; ++t) {
                    acc[t][j] = fmaf(xv[t].x, uv.x, acc[t][j]);
                    acc[t][j] = fmaf(xv[t].y, uv.y, acc[t][j]);
                    acc[t][j] = fmaf(xv[t].z, uv.z, acc[t][j]);
                    acc[t][j] = fmaf(xv[t].w, uv.w, acc[t][j]);
                }
            }
        }
        // halving butterfly over 16 m-lanes; final: lane holds (t=(m>>2)&3, j=m&3)
        float v8[8];
        {
            bool b = (lane >> 3) & 1;
#pragma unroll
            for (int i = 0; i < 8; ++i) {
                float lo = acc[i >> 2][i & 3];
                float hi = acc[2 + (i >> 2)][i & 3];
                float send = b ? lo : hi;
                float keep = b ? hi : lo;
                v8[i] = keep + __shfl_xor(send, 8, 64);
            }
        }
        float v4[4];
        {
            bool b = (lane >> 2) & 1;
#pragma unroll
            for (int i = 0; i < 4; ++i) {
                float send = b ? v8[i] : v8[4 + i];
                float keep = b ? v8[4 + i] : v8[i];
                v4[i] = keep + __shfl_xor(send, 4, 64);
            }
        }
        float v2[2];
        {
            bool b = (lane >> 1) & 1;
#pragma unroll
            for (int i = 0; i < 2; ++i) {
                float send = b ? v4[i] : v4[2 + i];
                float keep = b ? v4[2 + i] : v4[i];
                v2[i] = keep + __shfl_xor(send, 2, 64);
            }
        }
        float r;
        {
            bool b = lane & 1;
            float send = b ? v2[0] : v2[1];
            float keep = b ? v2[1] : v2[0];
            r = keep + __shfl_xor(send, 1, 64);
        }
        int t = (lane >> 2) & 3;
        int h = 4 * g + (lane & 3);
        int tok = tb + t;
        int bb = tok >> 11, s = tok & (S - 1);
        scores[((size_t)(bb * H + h)) * S + s] = r;
    }
}

// ---------------------------------------------------------------- masked softmax over S per (b,h)
__global__ __launch_bounds__(256) void softmax_kernel(float* __restrict__ scores,
                                                      const int* __restrict__ mask) {
    int bh = blockIdx.x;
    int b = bh >> 4;
    float* row = scores + (size_t)bh * S;
    const int* mrow = mask + (size_t)b * S;
    int t = threadIdx.x, lane = t & 63, wid = t >> 6;
    float vals[8];
    float mx = -1e30f;
#pragma unroll
    for (int i = 0; i < 8; ++i) {
        int s = i * 256 + t;
        float v = row[s];
        if (mrow[s] == 0) v = -1e30f;
        vals[i] = v;
        mx = fmaxf(mx, v);
    }
    __shared__ float redm[4], reds[4];
#pragma unroll
    for (int off = 32; off > 0; off >>= 1) mx = fmaxf(mx, __shfl_down(mx, off, 64));
    if (lane == 0) redm[wid] = mx;
    __syncthreads();
    mx = fmaxf(fmaxf(redm[0], redm[1]), fmaxf(redm[2], redm[3]));
    float sum = 0.f;
#pragma unroll
    for (int i = 0; i < 8; ++i) {
        float p = __expf(vals[i] - mx);
        vals[i] = p;
        sum += p;
    }
#pragma unroll
    for (int off = 32; off > 0; off >>= 1) sum += __shfl_down(sum, off, 64);
    if (lane == 0) reds[wid] = sum;
    __syncthreads();
    sum = reds[0] + reds[1] + reds[2] + reds[3];
    float inv = 1.f / sum;
#pragma unroll
    for (int i = 0; i < 8; ++i) row[i * 256 + t] = vals[i] * inv;
}

// ---------------------------------------------------------------- xbar[b][h][:] += sum_s attn * x  (atomic partial)
// mask-skip: attn is exactly 0 for masked tokens -> skip their x loads (uniform branch).
__global__ __launch_bounds__(256) void pool_kernel(const float* __restrict__ x,
                                                   const float* __restrict__ attn,
                                                   const int* __restrict__ mask,
                                                   float* __restrict__ xbar) {
    int sp = blockIdx.x, b = blockIdx.y;
    int t = threadIdx.x;
    __shared__ float at[H][PCHUNK];  // 8 KB
    __shared__ int mk[PCHUNK];
    for (int i = t; i < H * PCHUNK; i += 256) {
        int h = i / PCHUNK, s = i % PCHUNK;
        at[h][s] = attn[((size_t)(b * H + h)) * S + sp * PCHUNK + s];
    }
    for (int i = t; i < PCHUNK; i += 256) mk[i] = mask[(size_t)b * S + sp * PCHUNK + i];
    __syncthreads();
    const float4* xr = (const float4*)(x + ((size_t)(b * S) + sp * PCHUNK) * E);
    float4 acc[H];
#pragma unroll
    for (int h = 0; h < H; ++h) acc[h] = make_float4(0.f, 0.f, 0.f, 0.f);
    for (int s = 0; s < PCHUNK; ++s) {
        if (mk[s] == 0) continue;
        float4 xv = xr[(size_t)s * (E / 4) + t];
#pragma unroll
        for (int h = 0; h < H; ++h) {
            float a = at[h][s];
            acc[h].x = fmaf(a, xv.x, acc[h].x);
            acc[h].y = fmaf(a, xv.y, acc[h].y);
            acc[h].z = fmaf(a, xv.z, acc[h].z);
            acc[h].w = fmaf(a, xv.w, acc[h].w);
        }
    }
    float* xb = xbar + (size_t)b * H * E + t * 4;
#pragma unroll
    for (int h = 0; h < H; ++h) {
        atomicAdd(&xb[h * E + 0], acc[h].x);
        atomicAdd(&xb[h * E + 1], acc[h].y);
        atomicAdd(&xb[h * E + 2], acc[h].z);
        atomicAdd(&xb[h * E + 3], acc[h].w);
    }
}

// ---------------------------------------------------------------- ctx[b][c] = bv[c] + Wv[c] . xbar[b][h(c)]
__global__ __launch_bounds__(256) void ctx_kernel(const float* __restrict__ W,
                                                  const float* __restrict__ bqkv,
                                                  const float* __restrict__ xbar,
                                                  float* __restrict__ ctx) {
    int cb = blockIdx.x, b = blockIdx.y, t = threadIdx.x;
    int c = cb * 256 + t;
    int h0 = cb * 4;
    __shared__ float xls[4 * E];  // 16 KB
    const float4* xbp = (const float4*)(xbar + ((size_t)b * H + h0) * E);
    for (int i = t; i < 4 * E / 4; i += 256) ((float4*)xls)[i] = xbp[i];
    __syncthreads();
    int h = c >> 6;
    const float4* wr = (const float4*)(W + ((size_t)(2 * E + c)) * E);
    const float4* xl = (const float4*)(xls + (h - h0) * E);
    float acc = bqkv[2 * E + c];
#pragma unroll 4
    for (int e4 = 0; e4 < E / 4; ++e4) {
        float4 w = wr[e4], xv = xl[e4];
        acc = fmaf(w.x, xv.x, acc); acc = fmaf(w.y, xv.y, acc);
        acc = fmaf(w.z, xv.z, acc); acc = fmaf(w.w, xv.w, acc);
    }
    ctx[(size_t)b * E + c] = acc;
}

// ---------------------------------------------------------------- out[b][o] = ob[o] + Wo[o] . ctx[b]
__global__ __launch_bounds__(256) void outproj_kernel(const float* __restrict__ Wo,
                                                      const float* __restrict__ ob,
                                                      const float* __restrict__ ctx,
                                                      float* __restrict__ outpre) {
    int obk = blockIdx.x, b = blockIdx.y, t = threadIdx.x;
    int o = obk * 256 + t;
    __shared__ float cl[E];  // 4 KB
    const float4* cp = (const float4*)(ctx + (size_t)b * E);
    for (int i = t; i < E / 4; i += 256) ((float4*)cl)[i] = cp[i];
    __syncthreads();
    const float4* wr = (const float4*)(Wo + (size_t)o * E);
    const float4* cl4 = (const float4*)cl;
    float acc = ob[o];
#pragma unroll 4
    for (int e4 = 0; e4 < E / 4; ++e4) {
        float4 w = wr[e4], cv = cl4[e4];
        acc = fmaf(w.x, cv.x, acc); acc = fmaf(w.y, cv.y, acc);
        acc = fmaf(w.z, cv.z, acc); acc = fmaf(w.w, cv.w, acc);
    }
    outpre[(size_t)b * E + o] = acc;
}

// ---------------------------------------------------------------- LayerNorm over E per b
__global__ __launch_bounds__(256) void ln_kernel(const float* __restrict__ outpre,
                                                 const float* __restrict__ g,
                                                 const float* __restrict__ bb,
                                                 float* __restrict__ out) {
    int b = blockIdx.x, t = threadIdx.x, lane = t & 63, wid = t >> 6;
    const float4* row = (const float4*)(outpre + (size_t)b * E);
    float4 v = row[t];
    float s = v.x + v.y + v.z + v.w;
    float sq = v.x * v.x + v.y * v.y + v.z * v.z + v.w * v.w;
    __shared__ float rs[4], rq[4];
#pragma unroll
    for (int off = 32; off > 0; off >>= 1) {
        s += __shfl_down(s, off, 64);
        sq += __shfl_down(sq, off, 64);
    }
    if (lane == 0) { rs[wid] = s; rq[wid] = sq; }
    __syncthreads();
    s = rs[0] + rs[1] + rs[2] + rs[3];
    sq = rq[0] + rq[1] + rq[2] + rq[3];
    float mean = s * (1.f / E);
    float var = sq * (1.f / E) - mean * mean;
    float inv = rsqrtf(var + 1e-5f);
    float4 gv = ((const float4*)g)[t];
    float4 bv = ((const float4*)bb)[t];
    float4 o;
    o.x = (v.x - mean) * inv * gv.x + bv.x;
    o.y = (v.y - mean) * inv * gv.y + bv.y;
    o.z = (v.z - mean) * inv * gv.z + bv.z;
    o.w = (v.w - mean) * inv * gv.w + bv.w;
    ((float4*)(out + (size_t)b * E))[t] = o;
}

extern "C" void kernel_launch(void* const* d_in, const int* in_sizes, int n_in,
                              void* d_out, int out_size, void* d_ws, size_t ws_size,
                              hipStream_t stream) {
    const float* x    = (const float*)d_in[0];
    const int*   mask = (const int*)d_in[1];
    const float* seed = (const float*)d_in[2];
    const float* W    = (const float*)d_in[3];  // (3E, E)
    const float* bqkv = (const float*)d_in[4];  // (3E,)
    const float* Wo   = (const float*)d_in[5];  // (E, E)
    const float* ob   = (const float*)d_in[6];  // (E,)
    const float* g    = (const float*)d_in[7];
    const float* lb   = (const float*)d_in[8];
    float* out = (float*)d_out;

    float* ws = (float*)d_ws;
    float* q      = ws;                      // 1024
    float* u      = q + E;                   // 16384
    float* scores = u + H * E;               // B*H*S = 1,048,576
    float* xbar   = scores + (size_t)B * H * S;  // B*H*E = 524,288
    float* ctx    = xbar + (size_t)B * H * E;    // B*E
    float* outpre = ctx + (size_t)B * E;         // B*E

    hipMemsetAsync(xbar, 0, (size_t)B * H * E * sizeof(float), stream);

    qproj_kernel<<<256, 256, 0, stream>>>(W, bqkv, seed, q);
    uproj_kernel<<<dim3(E / 256, H), 256, 0, stream>>>(W, q, u);
    scores_kernel<<<512, 512, 0, stream>>>(x, u, scores);
    softmax_kernel<<<B * H, 256, 0, stream>>>(scores, mask);
    pool_kernel<<<dim3(PSPLIT, B), 256, 0, stream>>>(x, scores, mask, xbar);
    ctx_kernel<<<dim3(E / 256, B), 256, 0, stream>>>(W, bqkv, xbar, ctx);
    outproj_kernel<<<dim3(E / 256, B), 256, 0, stream>>>(Wo, ob, ctx, outpre);
    ln_kernel<<<B, 256, 0, stream>>>(outpre, g, lb, out);
}

// Round 3
// 365.166 us; speedup vs baseline: 1.5234x; 1.3648x over previous
//
#include <hip/hip_runtime.h>
#include <math.h>

#define E 1024
#define H 16
#define HD 64
#define B 32
#define S 2048
#define PSPLIT 32
#define PCHUNK (S / PSPLIT)  // 64

// ---------------------------------------------------------------- q = Wq @ seed + bq
__global__ __launch_bounds__(256) void qproj_kernel(const float* __restrict__ W,
                                                    const float* __restrict__ bqkv,
                                                    const float* __restrict__ seed,
                                                    float* __restrict__ q) {
    int gw = (blockIdx.x * 256 + threadIdx.x) >> 6;  // e index
    int lane = threadIdx.x & 63;
    if (gw >= E) return;
    const float4* row = (const float4*)(W + (size_t)gw * E);
    const float4* sd = (const float4*)seed;
    float acc = 0.f;
#pragma unroll
    for (int k = 0; k < 4; ++k) {
        float4 w4 = row[k * 64 + lane];
        float4 s4 = sd[k * 64 + lane];
        acc = fmaf(w4.x, s4.x, acc); acc = fmaf(w4.y, s4.y, acc);
        acc = fmaf(w4.z, s4.z, acc); acc = fmaf(w4.w, s4.w, acc);
    }
#pragma unroll
    for (int off = 32; off > 0; off >>= 1) acc += __shfl_down(acc, off, 64);
    if (lane == 0) q[gw] = acc + bqkv[gw];
}

// ---------------------------------------------------------------- u[h][e] = scale * sum_d q[h*64+d] * Wk[h*64+d][e]
__global__ __launch_bounds__(256) void uproj_kernel(const float* __restrict__ W,
                                                    const float* __restrict__ q,
                                                    float* __restrict__ u) {
    int h = blockIdx.y;
    int e = blockIdx.x * 256 + threadIdx.x;
    __shared__ float qs[HD];
    if (threadIdx.x < HD) qs[threadIdx.x] = q[h * HD + threadIdx.x];
    __syncthreads();
    const float* Wk = W + ((size_t)(E + h * HD)) * E + e;
    float acc = 0.f;
#pragma unroll 8
    for (int d = 0; d < HD; ++d) acc = fmaf(qs[d], Wk[(size_t)d * E], acc);
    u[h * E + e] = acc * 0.125f;  // 1/sqrt(64)
}

// ---------------------------------------------------------------- scores[b][h][s] = u[h] . x[b][s]
// v3: wave handles 16 tokens. lane (m = lane&15, g = lane>>4) owns tokens tb+g*4+{0..3}
// and e-slice m*4 + k*64. x loads: 1KB/instr fully coalesced. acc[4 tok][16 h] = 64 VGPRs.
// u from 64KB swizzled LDS, 1 b128 per (k,h), 4-way g-broadcast, amortized over 4 tokens.
// End: 4-step packing butterfly over 16 m-lanes; lane m holds v=4m+j -> full-line stores.
// Masked tokens: skip x load (their scores are junk; softmax re-masks them anyway).
__global__ __launch_bounds__(512, 4) void scores_kernel(const float* __restrict__ x,
                                                        const int* __restrict__ mask,
                                                        const float* __restrict__ u,
                                                        float* __restrict__ scores) {
    __shared__ float4 uT[4096];  // [e4][h^(e4&7)] -> 64 KB
    for (int idx = threadIdx.x; idx < 4096; idx += 512) {
        int h = idx >> 8, e4 = idx & 255;
        uT[e4 * 16 + (h ^ (e4 & 7))] = ((const float4*)(u + (size_t)h * E))[e4];
    }
    __syncthreads();

    int lane = threadIdx.x & 63;
    int wid = threadIdx.x >> 6;
    int m = lane & 15, g = lane >> 4;
    int gwave = blockIdx.x * 8 + wid;   // 0..4095
    int tb = gwave * 16;
    int tok0 = tb + g * 4;              // my 4 tokens: tok0..tok0+3 (same batch row: tok0%4==0)
    int b0 = tok0 >> 11;
    int s0 = tok0 & (S - 1);

    int mk[4];
#pragma unroll
    for (int t = 0; t < 4; ++t) mk[t] = mask[(size_t)b0 * S + s0 + t];

    const float* xb = x + (size_t)tok0 * E + m * 4;

    float acc[64];
#pragma unroll
    for (int i = 0; i < 64; ++i) acc[i] = 0.f;

    for (int k = 0; k < 16; ++k) {
        float4 xv[4];
#pragma unroll
        for (int t = 0; t < 4; ++t) {
            xv[t] = make_float4(0.f, 0.f, 0.f, 0.f);
            if (mk[t]) xv[t] = *(const float4*)(xb + (size_t)t * E + k * 64);
        }
        const float4* uk = uT + k * 256 + m * 16;
        int sw = m & 7;
#pragma unroll
        for (int h = 0; h < 16; ++h) {
            float4 uv = uk[h ^ sw];
#pragma unroll
            for (int t = 0; t < 4; ++t) {
                acc[t * 16 + h] = fmaf(xv[t].x, uv.x, acc[t * 16 + h]);
                acc[t * 16 + h] = fmaf(xv[t].y, uv.y, acc[t * 16 + h]);
                acc[t * 16 + h] = fmaf(xv[t].z, uv.z, acc[t * 16 + h]);
                acc[t * 16 + h] = fmaf(xv[t].w, uv.w, acc[t * 16 + h]);
            }
        }
    }

    // packing butterfly over the 16 m-lanes: 64 -> 32 -> 16 -> 8 -> 4 values
    float v32[32];
    {
        bool up = (lane & 8) != 0;
#pragma unroll
        for (int i = 0; i < 32; ++i) {
            float lo = acc[i], hi = acc[32 + i];
            float send = up ? lo : hi, keep = up ? hi : lo;
            v32[i] = keep + __shfl_xor(send, 8, 64);
        }
    }
    float v16[16];
    {
        bool up = (lane & 4) != 0;
#pragma unroll
        for (int i = 0; i < 16; ++i) {
            float lo = v32[i], hi = v32[16 + i];
            float send = up ? lo : hi, keep = up ? hi : lo;
            v16[i] = keep + __shfl_xor(send, 4, 64);
        }
    }
    float v8a[8];
    {
        bool up = (lane & 2) != 0;
#pragma unroll
        for (int i = 0; i < 8; ++i) {
            float lo = v16[i], hi = v16[8 + i];
            float send = up ? lo : hi, keep = up ? hi : lo;
            v8a[i] = keep + __shfl_xor(send, 2, 64);
        }
    }
    float v4a[4];
    {
        bool up = (lane & 1) != 0;
#pragma unroll
        for (int i = 0; i < 4; ++i) {
            float lo = v8a[i], hi = v8a[4 + i];
            float send = up ? lo : hi, keep = up ? hi : lo;
            v4a[i] = keep + __shfl_xor(send, 1, 64);
        }
    }
    // lane m holds v = 4m+j: token offset t = m>>2, head h = 4*(m&3)+j
    int t = m >> 2;
    int h0 = (m & 3) * 4;
    int tok = tok0 + t;
    int bb = tok >> 11, s = tok & (S - 1);
#pragma unroll
    for (int j = 0; j < 4; ++j)
        scores[((size_t)(bb * H + h0 + j)) * S + s] = v4a[j];
}

// ---------------------------------------------------------------- masked softmax over S per (b,h)
__global__ __launch_bounds__(256) void softmax_kernel(float* __restrict__ scores,
                                                      const int* __restrict__ mask) {
    int bh = blockIdx.x;
    int b = bh >> 4;
    float* row = scores + (size_t)bh * S;
    const int* mrow = mask + (size_t)b * S;
    int t = threadIdx.x, lane = t & 63, wid = t >> 6;
    float vals[8];
    float mx = -1e30f;
#pragma unroll
    for (int i = 0; i < 8; ++i) {
        int s = i * 256 + t;
        float v = row[s];
        if (mrow[s] == 0) v = -1e30f;
        vals[i] = v;
        mx = fmaxf(mx, v);
    }
    __shared__ float redm[4], reds[4];
#pragma unroll
    for (int off = 32; off > 0; off >>= 1) mx = fmaxf(mx, __shfl_down(mx, off, 64));
    if (lane == 0) redm[wid] = mx;
    __syncthreads();
    mx = fmaxf(fmaxf(redm[0], redm[1]), fmaxf(redm[2], redm[3]));
    float sum = 0.f;
#pragma unroll
    for (int i = 0; i < 8; ++i) {
        float p = __expf(vals[i] - mx);
        vals[i] = p;
        sum += p;
    }
#pragma unroll
    for (int off = 32; off > 0; off >>= 1) sum += __shfl_down(sum, off, 64);
    if (lane == 0) reds[wid] = sum;
    __syncthreads();
    sum = reds[0] + reds[1] + reds[2] + reds[3];
    float inv = 1.f / sum;
#pragma unroll
    for (int i = 0; i < 8; ++i) row[i * 256 + t] = vals[i] * inv;
}

// ---------------------------------------------------------------- xbar[b][h][:] += sum_s attn * x  (atomic partial)
__global__ __launch_bounds__(256) void pool_kernel(const float* __restrict__ x,
                                                   const float* __restrict__ attn,
                                                   const int* __restrict__ mask,
                                                   float* __restrict__ xbar) {
    int sp = blockIdx.x, b = blockIdx.y;
    int t = threadIdx.x;
    __shared__ float at[H][PCHUNK];  // 4 KB
    __shared__ int mk[PCHUNK];
    for (int i = t; i < H * PCHUNK; i += 256) {
        int h = i / PCHUNK, s = i % PCHUNK;
        at[h][s] = attn[((size_t)(b * H + h)) * S + sp * PCHUNK + s];
    }
    for (int i = t; i < PCHUNK; i += 256) mk[i] = mask[(size_t)b * S + sp * PCHUNK + i];
    __syncthreads();
    const float4* xr = (const float4*)(x + ((size_t)(b * S) + sp * PCHUNK) * E);
    float4 acc[H];
#pragma unroll
    for (int h = 0; h < H; ++h) acc[h] = make_float4(0.f, 0.f, 0.f, 0.f);
    for (int s = 0; s < PCHUNK; ++s) {
        if (mk[s] == 0) continue;
        float4 xv = xr[(size_t)s * (E / 4) + t];
#pragma unroll
        for (int h = 0; h < H; ++h) {
            float a = at[h][s];
            acc[h].x = fmaf(a, xv.x, acc[h].x);
            acc[h].y = fmaf(a, xv.y, acc[h].y);
            acc[h].z = fmaf(a, xv.z, acc[h].z);
            acc[h].w = fmaf(a, xv.w, acc[h].w);
        }
    }
    float* xb = xbar + (size_t)b * H * E + t * 4;
#pragma unroll
    for (int h = 0; h < H; ++h) {
        atomicAdd(&xb[h * E + 0], acc[h].x);
        atomicAdd(&xb[h * E + 1], acc[h].y);
        atomicAdd(&xb[h * E + 2], acc[h].z);
        atomicAdd(&xb[h * E + 3], acc[h].w);
    }
}

// ---------------------------------------------------------------- ctx[b][c] = bv[c] + Wv[c] . xbar[b][h(c)]
__global__ __launch_bounds__(256) void ctx_kernel(const float* __restrict__ W,
                                                  const float* __restrict__ bqkv,
                                                  const float* __restrict__ xbar,
                                                  float* __restrict__ ctx) {
    int cb = blockIdx.x, b = blockIdx.y, t = threadIdx.x;
    int c = cb * 256 + t;
    int h0 = cb * 4;
    __shared__ float xls[4 * E];  // 16 KB
    const float4* xbp = (const float4*)(xbar + ((size_t)b * H + h0) * E);
    for (int i = t; i < 4 * E / 4; i += 256) ((float4*)xls)[i] = xbp[i];
    __syncthreads();
    int h = c >> 6;
    const float4* wr = (const float4*)(W + ((size_t)(2 * E + c)) * E);
    const float4* xl = (const float4*)(xls + (h - h0) * E);
    float acc = bqkv[2 * E + c];
#pragma unroll 4
    for (int e4 = 0; e4 < E / 4; ++e4) {
        float4 w = wr[e4], xv = xl[e4];
        acc = fmaf(w.x, xv.x, acc); acc = fmaf(w.y, xv.y, acc);
        acc = fmaf(w.z, xv.z, acc); acc = fmaf(w.w, xv.w, acc);
    }
    ctx[(size_t)b * E + c] = acc;
}

// ---------------------------------------------------------------- out[b][o] = ob[o] + Wo[o] . ctx[b]
__global__ __launch_bounds__(256) void outproj_kernel(const float* __restrict__ Wo,
                                                      const float* __restrict__ ob,
                                                      const float* __restrict__ ctx,
                                                      float* __restrict__ outpre) {
    int obk = blockIdx.x, b = blockIdx.y, t = threadIdx.x;
    int o = obk * 256 + t;
    __shared__ float cl[E];  // 4 KB
    const float4* cp = (const float4*)(ctx + (size_t)b * E);
    for (int i = t; i < E / 4; i += 256) ((float4*)cl)[i] = cp[i];
    __syncthreads();
    const float4* wr = (const float4*)(Wo + (size_t)o * E);
    const float4* cl4 = (const float4*)cl;
    float acc = ob[o];
#pragma unroll 4
    for (int e4 = 0; e4 < E / 4; ++e4) {
        float4 w = wr[e4], cv = cl4[e4];
        acc = fmaf(w.x, cv.x, acc); acc = fmaf(w.y, cv.y, acc);
        acc = fmaf(w.z, cv.z, acc); acc = fmaf(w.w, cv.w, acc);
    }
    outpre[(size_t)b * E + o] = acc;
}

// ---------------------------------------------------------------- LayerNorm over E per b
__global__ __launch_bounds__(256) void ln_kernel(const float* __restrict__ outpre,
                                                 const float* __restrict__ g,
                                                 const float* __restrict__ bb,
                                                 float* __restrict__ out) {
    int b = blockIdx.x, t = threadIdx.x, lane = t & 63, wid = t >> 6;
    const float4* row = (const float4*)(outpre + (size_t)b * E);
    float4 v = row[t];
    float s = v.x + v.y + v.z + v.w;
    float sq = v.x * v.x + v.y * v.y + v.z * v.z + v.w * v.w;
    __shared__ float rs[4], rq[4];
#pragma unroll
    for (int off = 32; off > 0; off >>= 1) {
        s += __shfl_down(s, off, 64);
        sq += __shfl_down(sq, off, 64);
    }
    if (lane == 0) { rs[wid] = s; rq[wid] = sq; }
    __syncthreads();
    s = rs[0] + rs[1] + rs[2] + rs[3];
    sq = rq[0] + rq[1] + rq[2] + rq[3];
    float mean = s * (1.f / E);
    float var = sq * (1.f / E) - mean * mean;
    float inv = rsqrtf(var + 1e-5f);
    float4 gv = ((const float4*)g)[t];
    float4 bv = ((const float4*)bb)[t];
    float4 o;
    o.x = (v.x - mean) * inv * gv.x + bv.x;
    o.y = (v.y - mean) * inv * gv.y + bv.y;
    o.z = (v.z - mean) * inv * gv.z + bv.z;
    o.w = (v.w - mean) * inv * gv.w + bv.w;
    ((float4*)(out + (size_t)b * E))[t] = o;
}

extern "C" void kernel_launch(void* const* d_in, const int* in_sizes, int n_in,
                              void* d_out, int out_size, void* d_ws, size_t ws_size,
                              hipStream_t stream) {
    const float* x    = (const float*)d_in[0];
    const int*   mask = (const int*)d_in[1];
    const float* seed = (const float*)d_in[2];
    const float* W    = (const float*)d_in[3];  // (3E, E)
    const float* bqkv = (const float*)d_in[4];  // (3E,)
    const float* Wo   = (const float*)d_in[5];  // (E, E)
    const float* ob   = (const float*)d_in[6];  // (E,)
    const float* g    = (const float*)d_in[7];
    const float* lb   = (const float*)d_in[8];
    float* out = (float*)d_out;

    float* ws = (float*)d_ws;
    float* q      = ws;                      // 1024
    float* u      = q + E;                   // 16384
    float* scores = u + H * E;               // B*H*S = 1,048,576
    float* xbar   = scores + (size_t)B * H * S;  // B*H*E = 524,288
    float* ctx    = xbar + (size_t)B * H * E;    // B*E
    float* outpre = ctx + (size_t)B * E;         // B*E

    hipMemsetAsync(xbar, 0, (size_t)B * H * E * sizeof(float), stream);

    qproj_kernel<<<256, 256, 0, stream>>>(W, bqkv, seed, q);
    uproj_kernel<<<dim3(E / 256, H), 256, 0, stream>>>(W, q, u);
    scores_kernel<<<512, 512, 0, stream>>>(x, mask, u, scores);
    softmax_kernel<<<B * H, 256, 0, stream>>>(scores, mask);
    pool_kernel<<<dim3(PSPLIT, B), 256, 0, stream>>>(x, scores, mask, xbar);
    ctx_kernel<<<dim3(E / 256, B), 256, 0, stream>>>(W, bqkv, xbar, ctx);
    outproj_kernel<<<dim3(E / 256, B), 256, 0, stream>>>(Wo, ob, ctx, outpre);
    ln_kernel<<<B, 256, 0, stream>>>(outpre, g, lb, out);
}

// Round 4
// 227.209 us; speedup vs baseline: 2.4484x; 1.6072x over previous
//
#include <hip/hip_runtime.h>
#include <math.h>

#define E 1024
#define H 16
#define HD 64
#define B 32
#define S 2048
#define PSPLIT 32
#define PCHUNK (S / PSPLIT)  // 64  (atomic fallback path)
#define PS 8
#define PTOK (S / PS)        // 256 (partials path)

// ---------------------------------------------------------------- q = Wq @ seed + bq
__global__ __launch_bounds__(256) void qproj_kernel(const float* __restrict__ W,
                                                    const float* __restrict__ bqkv,
                                                    const float* __restrict__ seed,
                                                    float* __restrict__ q) {
    int gw = (blockIdx.x * 256 + threadIdx.x) >> 6;  // e index
    int lane = threadIdx.x & 63;
    if (gw >= E) return;
    const float4* row = (const float4*)(W + (size_t)gw * E);
    const float4* sd = (const float4*)seed;
    float acc = 0.f;
#pragma unroll
    for (int k = 0; k < 4; ++k) {
        float4 w4 = row[k * 64 + lane];
        float4 s4 = sd[k * 64 + lane];
        acc = fmaf(w4.x, s4.x, acc); acc = fmaf(w4.y, s4.y, acc);
        acc = fmaf(w4.z, s4.z, acc); acc = fmaf(w4.w, s4.w, acc);
    }
#pragma unroll
    for (int off = 32; off > 0; off >>= 1) acc += __shfl_down(acc, off, 64);
    if (lane == 0) q[gw] = acc + bqkv[gw];
}

// ---------------------------------------------------------------- u[h][e] = scale * sum_d q[h*64+d] * Wk[h*64+d][e]
__global__ __launch_bounds__(256) void uproj_kernel(const float* __restrict__ W,
                                                    const float* __restrict__ q,
                                                    float* __restrict__ u) {
    int h = blockIdx.y;
    int e = blockIdx.x * 256 + threadIdx.x;
    __shared__ float qs[HD];
    if (threadIdx.x < HD) qs[threadIdx.x] = q[h * HD + threadIdx.x];
    __syncthreads();
    const float* Wk = W + ((size_t)(E + h * HD)) * E + e;
    float acc = 0.f;
#pragma unroll 8
    for (int d = 0; d < HD; ++d) acc = fmaf(qs[d], Wk[(size_t)d * E], acc);
    u[h * E + e] = acc * 0.125f;  // 1/sqrt(64)
}

// ---------------------------------------------------------------- scores[b][h][s] = u[h] . x[b][s]
__global__ __launch_bounds__(512, 4) void scores_kernel(const float* __restrict__ x,
                                                        const int* __restrict__ mask,
                                                        const float* __restrict__ u,
                                                        float* __restrict__ scores) {
    __shared__ float4 uT[4096];  // [e4][h^(e4&7)] -> 64 KB
    for (int idx = threadIdx.x; idx < 4096; idx += 512) {
        int h = idx >> 8, e4 = idx & 255;
        uT[e4 * 16 + (h ^ (e4 & 7))] = ((const float4*)(u + (size_t)h * E))[e4];
    }
    __syncthreads();

    int lane = threadIdx.x & 63;
    int wid = threadIdx.x >> 6;
    int m = lane & 15, g = lane >> 4;
    int gwave = blockIdx.x * 8 + wid;   // 0..4095
    int tb = gwave * 16;
    int tok0 = tb + g * 4;              // my 4 tokens
    int b0 = tok0 >> 11;
    int s0 = tok0 & (S - 1);

    int mk[4];
#pragma unroll
    for (int t = 0; t < 4; ++t) mk[t] = mask[(size_t)b0 * S + s0 + t];

    const float* xb = x + (size_t)tok0 * E + m * 4;

    float acc[64];
#pragma unroll
    for (int i = 0; i < 64; ++i) acc[i] = 0.f;

    for (int k = 0; k < 16; ++k) {
        float4 xv[4];
#pragma unroll
        for (int t = 0; t < 4; ++t) {
            xv[t] = make_float4(0.f, 0.f, 0.f, 0.f);
            if (mk[t]) xv[t] = *(const float4*)(xb + (size_t)t * E + k * 64);
        }
        const float4* uk = uT + k * 256 + m * 16;
        int sw = m & 7;
#pragma unroll
        for (int h = 0; h < 16; ++h) {
            float4 uv = uk[h ^ sw];
#pragma unroll
            for (int t = 0; t < 4; ++t) {
                acc[t * 16 + h] = fmaf(xv[t].x, uv.x, acc[t * 16 + h]);
                acc[t * 16 + h] = fmaf(xv[t].y, uv.y, acc[t * 16 + h]);
                acc[t * 16 + h] = fmaf(xv[t].z, uv.z, acc[t * 16 + h]);
                acc[t * 16 + h] = fmaf(xv[t].w, uv.w, acc[t * 16 + h]);
            }
        }
    }

    // packing butterfly over the 16 m-lanes: 64 -> 32 -> 16 -> 8 -> 4 values
    float v32[32];
    {
        bool up = (lane & 8) != 0;
#pragma unroll
        for (int i = 0; i < 32; ++i) {
            float lo = acc[i], hi = acc[32 + i];
            float send = up ? lo : hi, keep = up ? hi : lo;
            v32[i] = keep + __shfl_xor(send, 8, 64);
        }
    }
    float v16[16];
    {
        bool up = (lane & 4) != 0;
#pragma unroll
        for (int i = 0; i < 16; ++i) {
            float lo = v32[i], hi = v32[16 + i];
            float send = up ? lo : hi, keep = up ? hi : lo;
            v16[i] = keep + __shfl_xor(send, 4, 64);
        }
    }
    float v8a[8];
    {
        bool up = (lane & 2) != 0;
#pragma unroll
        for (int i = 0; i < 8; ++i) {
            float lo = v16[i], hi = v16[8 + i];
            float send = up ? lo : hi, keep = up ? hi : lo;
            v8a[i] = keep + __shfl_xor(send, 2, 64);
        }
    }
    float v4a[4];
    {
        bool up = (lane & 1) != 0;
#pragma unroll
        for (int i = 0; i < 4; ++i) {
            float lo = v8a[i], hi = v8a[4 + i];
            float send = up ? lo : hi, keep = up ? hi : lo;
            v4a[i] = keep + __shfl_xor(send, 1, 64);
        }
    }
    int t = m >> 2;
    int h0 = (m & 3) * 4;
    int tok = tok0 + t;
    int bb = tok >> 11, s = tok & (S - 1);
#pragma unroll
    for (int j = 0; j < 4; ++j)
        scores[((size_t)(bb * H + h0 + j)) * S + s] = v4a[j];
}

// ---------------------------------------------------------------- masked softmax over S per (b,h)
__global__ __launch_bounds__(256) void softmax_kernel(float* __restrict__ scores,
                                                      const int* __restrict__ mask) {
    int bh = blockIdx.x;
    int b = bh >> 4;
    float* row = scores + (size_t)bh * S;
    const int* mrow = mask + (size_t)b * S;
    int t = threadIdx.x, lane = t & 63, wid = t >> 6;
    float vals[8];
    float mx = -1e30f;
#pragma unroll
    for (int i = 0; i < 8; ++i) {
        int s = i * 256 + t;
        float v = row[s];
        if (mrow[s] == 0) v = -1e30f;
        vals[i] = v;
        mx = fmaxf(mx, v);
    }
    __shared__ float redm[4], reds[4];
#pragma unroll
    for (int off = 32; off > 0; off >>= 1) mx = fmaxf(mx, __shfl_down(mx, off, 64));
    if (lane == 0) redm[wid] = mx;
    __syncthreads();
    mx = fmaxf(fmaxf(redm[0], redm[1]), fmaxf(redm[2], redm[3]));
    float sum = 0.f;
#pragma unroll
    for (int i = 0; i < 8; ++i) {
        float p = __expf(vals[i] - mx);
        vals[i] = p;
        sum += p;
    }
#pragma unroll
    for (int off = 32; off > 0; off >>= 1) sum += __shfl_down(sum, off, 64);
    if (lane == 0) reds[wid] = sum;
    __syncthreads();
    sum = reds[0] + reds[1] + reds[2] + reds[3];
    float inv = 1.f / sum;
#pragma unroll
    for (int i = 0; i < 8; ++i) row[i * 256 + t] = vals[i] * inv;
}

// ---------------------------------------------------------------- pool v2: partials, no atomics
// grid (PS, B), 512 threads; thread owns float2 e-slice; attn staged [s][h] in LDS
// (compute reads are wave-uniform b128 broadcasts). part[sp][b][h][e] plain stores.
__global__ __launch_bounds__(512) void pool2_kernel(const float* __restrict__ x,
                                                    const float* __restrict__ attn,
                                                    float* __restrict__ part) {
    int sp = blockIdx.x, b = blockIdx.y;
    int t = threadIdx.x;  // 0..511
    __shared__ float at[PTOK * H];  // [s][h], 16 KB
    for (int i = t; i < PTOK * H; i += 512) {
        int h = i & 15, s = i >> 4;
        at[i] = attn[((size_t)(b * H + h)) * S + sp * PTOK + s];
    }
    __syncthreads();
    const float2* xr = (const float2*)(x + ((size_t)b * S + sp * PTOK) * E);
    float2 acc[H];
#pragma unroll
    for (int h = 0; h < H; ++h) acc[h] = make_float2(0.f, 0.f);
#pragma unroll 2
    for (int s = 0; s < PTOK; ++s) {
        float2 xv = xr[(size_t)s * (E / 2) + t];
        const float4* ah = (const float4*)(at + s * H);
        float4 a0 = ah[0], a1 = ah[1], a2 = ah[2], a3 = ah[3];
        acc[0].x = fmaf(a0.x, xv.x, acc[0].x);  acc[0].y = fmaf(a0.x, xv.y, acc[0].y);
        acc[1].x = fmaf(a0.y, xv.x, acc[1].x);  acc[1].y = fmaf(a0.y, xv.y, acc[1].y);
        acc[2].x = fmaf(a0.z, xv.x, acc[2].x);  acc[2].y = fmaf(a0.z, xv.y, acc[2].y);
        acc[3].x = fmaf(a0.w, xv.x, acc[3].x);  acc[3].y = fmaf(a0.w, xv.y, acc[3].y);
        acc[4].x = fmaf(a1.x, xv.x, acc[4].x);  acc[4].y = fmaf(a1.x, xv.y, acc[4].y);
        acc[5].x = fmaf(a1.y, xv.x, acc[5].x);  acc[5].y = fmaf(a1.y, xv.y, acc[5].y);
        acc[6].x = fmaf(a1.z, xv.x, acc[6].x);  acc[6].y = fmaf(a1.z, xv.y, acc[6].y);
        acc[7].x = fmaf(a1.w, xv.x, acc[7].x);  acc[7].y = fmaf(a1.w, xv.y, acc[7].y);
        acc[8].x = fmaf(a2.x, xv.x, acc[8].x);  acc[8].y = fmaf(a2.x, xv.y, acc[8].y);
        acc[9].x = fmaf(a2.y, xv.x, acc[9].x);  acc[9].y = fmaf(a2.y, xv.y, acc[9].y);
        acc[10].x = fmaf(a2.z, xv.x, acc[10].x); acc[10].y = fmaf(a2.z, xv.y, acc[10].y);
        acc[11].x = fmaf(a2.w, xv.x, acc[11].x); acc[11].y = fmaf(a2.w, xv.y, acc[11].y);
        acc[12].x = fmaf(a3.x, xv.x, acc[12].x); acc[12].y = fmaf(a3.x, xv.y, acc[12].y);
        acc[13].x = fmaf(a3.y, xv.x, acc[13].x); acc[13].y = fmaf(a3.y, xv.y, acc[13].y);
        acc[14].x = fmaf(a3.z, xv.x, acc[14].x); acc[14].y = fmaf(a3.z, xv.y, acc[14].y);
        acc[15].x = fmaf(a3.w, xv.x, acc[15].x); acc[15].y = fmaf(a3.w, xv.y, acc[15].y);
    }
    float2* pp = (float2*)(part + ((size_t)(sp * B + b)) * (H * E));
#pragma unroll
    for (int h = 0; h < H; ++h) pp[h * (E / 2) + t] = acc[h];
}

// ---------------------------------------------------------------- xbar = sum_sp part[sp]
__global__ __launch_bounds__(256) void reduce8_kernel(const float* __restrict__ part,
                                                      float* __restrict__ xbar) {
    size_t i = (size_t)blockIdx.x * 256 + threadIdx.x;  // float4 index, B*H*E/4 total
    const float4* p = (const float4*)part;
    float4 s = p[i];
#pragma unroll
    for (int sp = 1; sp < PS; ++sp) {
        float4 v = p[(size_t)sp * (B * H * E / 4) + i];
        s.x += v.x; s.y += v.y; s.z += v.z; s.w += v.w;
    }
    ((float4*)xbar)[i] = s;
}

// ---------------------------------------------------------------- pool (atomic fallback)
__global__ __launch_bounds__(256) void pool_kernel(const float* __restrict__ x,
                                                   const float* __restrict__ attn,
                                                   const int* __restrict__ mask,
                                                   float* __restrict__ xbar) {
    int sp = blockIdx.x, b = blockIdx.y;
    int t = threadIdx.x;
    __shared__ float at[H][PCHUNK];
    __shared__ int mk[PCHUNK];
    for (int i = t; i < H * PCHUNK; i += 256) {
        int h = i / PCHUNK, s = i % PCHUNK;
        at[h][s] = attn[((size_t)(b * H + h)) * S + sp * PCHUNK + s];
    }
    for (int i = t; i < PCHUNK; i += 256) mk[i] = mask[(size_t)b * S + sp * PCHUNK + i];
    __syncthreads();
    const float4* xr = (const float4*)(x + ((size_t)(b * S) + sp * PCHUNK) * E);
    float4 acc[H];
#pragma unroll
    for (int h = 0; h < H; ++h) acc[h] = make_float4(0.f, 0.f, 0.f, 0.f);
    for (int s = 0; s < PCHUNK; ++s) {
        if (mk[s] == 0) continue;
        float4 xv = xr[(size_t)s * (E / 4) + t];
#pragma unroll
        for (int h = 0; h < H; ++h) {
            float a = at[h][s];
            acc[h].x = fmaf(a, xv.x, acc[h].x);
            acc[h].y = fmaf(a, xv.y, acc[h].y);
            acc[h].z = fmaf(a, xv.z, acc[h].z);
            acc[h].w = fmaf(a, xv.w, acc[h].w);
        }
    }
    float* xb = xbar + (size_t)b * H * E + t * 4;
#pragma unroll
    for (int h = 0; h < H; ++h) {
        atomicAdd(&xb[h * E + 0], acc[h].x);
        atomicAdd(&xb[h * E + 1], acc[h].y);
        atomicAdd(&xb[h * E + 2], acc[h].z);
        atomicAdd(&xb[h * E + 3], acc[h].w);
    }
}

// ---------------------------------------------------------------- ctx[b][c] = bv[c] + Wv[c] . xbar[b][h(c)]
__global__ __launch_bounds__(256) void ctx_kernel(const float* __restrict__ W,
                                                  const float* __restrict__ bqkv,
                                                  const float* __restrict__ xbar,
                                                  float* __restrict__ ctx) {
    int cb = blockIdx.x, b = blockIdx.y, t = threadIdx.x;
    int c = cb * 256 + t;
    int h0 = cb * 4;
    __shared__ float xls[4 * E];  // 16 KB
    const float4* xbp = (const float4*)(xbar + ((size_t)b * H + h0) * E);
    for (int i = t; i < 4 * E / 4; i += 256) ((float4*)xls)[i] = xbp[i];
    __syncthreads();
    int h = c >> 6;
    const float4* wr = (const float4*)(W + ((size_t)(2 * E + c)) * E);
    const float4* xl = (const float4*)(xls + (h - h0) * E);
    float acc = bqkv[2 * E + c];
#pragma unroll 4
    for (int e4 = 0; e4 < E / 4; ++e4) {
        float4 w = wr[e4], xv = xl[e4];
        acc = fmaf(w.x, xv.x, acc); acc = fmaf(w.y, xv.y, acc);
        acc = fmaf(w.z, xv.z, acc); acc = fmaf(w.w, xv.w, acc);
    }
    ctx[(size_t)b * E + c] = acc;
}

// ---------------------------------------------------------------- out[b][o] = ob[o] + Wo[o] . ctx[b]
__global__ __launch_bounds__(256) void outproj_kernel(const float* __restrict__ Wo,
                                                      const float* __restrict__ ob,
                                                      const float* __restrict__ ctx,
                                                      float* __restrict__ outpre) {
    int obk = blockIdx.x, b = blockIdx.y, t = threadIdx.x;
    int o = obk * 256 + t;
    __shared__ float cl[E];  // 4 KB
    const float4* cp = (const float4*)(ctx + (size_t)b * E);
    for (int i = t; i < E / 4; i += 256) ((float4*)cl)[i] = cp[i];
    __syncthreads();
    const float4* wr = (const float4*)(Wo + (size_t)o * E);
    const float4* cl4 = (const float4*)cl;
    float acc = ob[o];
#pragma unroll 4
    for (int e4 = 0; e4 < E / 4; ++e4) {
        float4 w = wr[e4], cv = cl4[e4];
        acc = fmaf(w.x, cv.x, acc); acc = fmaf(w.y, cv.y, acc);
        acc = fmaf(w.z, cv.z, acc); acc = fmaf(w.w, cv.w, acc);
    }
    outpre[(size_t)b * E + o] = acc;
}

// ---------------------------------------------------------------- LayerNorm over E per b
__global__ __launch_bounds__(256) void ln_kernel(const float* __restrict__ outpre,
                                                 const float* __restrict__ g,
                                                 const float* __restrict__ bb,
                                                 float* __restrict__ out) {
    int b = blockIdx.x, t = threadIdx.x, lane = t & 63, wid = t >> 6;
    const float4* row = (const float4*)(outpre + (size_t)b * E);
    float4 v = row[t];
    float s = v.x + v.y + v.z + v.w;
    float sq = v.x * v.x + v.y * v.y + v.z * v.z + v.w * v.w;
    __shared__ float rs[4], rq[4];
#pragma unroll
    for (int off = 32; off > 0; off >>= 1) {
        s += __shfl_down(s, off, 64);
        sq += __shfl_down(sq, off, 64);
    }
    if (lane == 0) { rs[wid] = s; rq[wid] = sq; }
    __syncthreads();
    s = rs[0] + rs[1] + rs[2] + rs[3];
    sq = rq[0] + rq[1] + rq[2] + rq[3];
    float mean = s * (1.f / E);
    float var = sq * (1.f / E) - mean * mean;
    float inv = rsqrtf(var + 1e-5f);
    float4 gv = ((const float4*)g)[t];
    float4 bv = ((const float4*)bb)[t];
    float4 o;
    o.x = (v.x - mean) * inv * gv.x + bv.x;
    o.y = (v.y - mean) * inv * gv.y + bv.y;
    o.z = (v.z - mean) * inv * gv.z + bv.z;
    o.w = (v.w - mean) * inv * gv.w + bv.w;
    ((float4*)(out + (size_t)b * E))[t] = o;
}

extern "C" void kernel_launch(void* const* d_in, const int* in_sizes, int n_in,
                              void* d_out, int out_size, void* d_ws, size_t ws_size,
                              hipStream_t stream) {
    const float* x    = (const float*)d_in[0];
    const int*   mask = (const int*)d_in[1];
    const float* seed = (const float*)d_in[2];
    const float* W    = (const float*)d_in[3];  // (3E, E)
    const float* bqkv = (const float*)d_in[4];  // (3E,)
    const float* Wo   = (const float*)d_in[5];  // (E, E)
    const float* ob   = (const float*)d_in[6];  // (E,)
    const float* g    = (const float*)d_in[7];
    const float* lb   = (const float*)d_in[8];
    float* out = (float*)d_out;

    float* ws = (float*)d_ws;
    float* q      = ws;                          // 1024
    float* u      = q + E;                       // 16384
    float* scores = u + H * E;                   // B*H*S = 1,048,576

    qproj_kernel<<<256, 256, 0, stream>>>(W, bqkv, seed, q);
    uproj_kernel<<<dim3(E / 256, H), 256, 0, stream>>>(W, q, u);
    scores_kernel<<<512, 512, 0, stream>>>(x, mask, u, scores);
    softmax_kernel<<<B * H, 256, 0, stream>>>(scores, mask);

    size_t base = (size_t)E + H * E + (size_t)B * H * S;
    size_t needA = (base + (size_t)PS * B * H * E + (size_t)B * H * E + 2 * (size_t)B * E) * sizeof(float);

    float* xbar;
    float* ctx;
    float* outpre;
    if (ws_size >= needA) {
        // partials path (no atomics)
        float* part = scores + (size_t)B * H * S;        // PS*B*H*E
        xbar   = part + (size_t)PS * B * H * E;          // B*H*E
        ctx    = xbar + (size_t)B * H * E;
        outpre = ctx + (size_t)B * E;
        pool2_kernel<<<dim3(PS, B), 512, 0, stream>>>(x, scores, part);
        reduce8_kernel<<<(B * H * E / 4) / 256, 256, 0, stream>>>(part, xbar);
    } else {
        // atomic fallback
        xbar   = scores + (size_t)B * H * S;
        ctx    = xbar + (size_t)B * H * E;
        outpre = ctx + (size_t)B * E;
        hipMemsetAsync(xbar, 0, (size_t)B * H * E * sizeof(float), stream);
        pool_kernel<<<dim3(PSPLIT, B), 256, 0, stream>>>(x, scores, mask, xbar);
    }

    ctx_kernel<<<dim3(E / 256, B), 256, 0, stream>>>(W, bqkv, xbar, ctx);
    outproj_kernel<<<dim3(E / 256, B), 256, 0, stream>>>(Wo, ob, ctx, outpre);
    ln_kernel<<<B, 256, 0, stream>>>(outpre, g, lb, out);
}